// Round 6
// baseline (235.452 us; speedup 1.0000x reference)
//
#include <hip/hip_runtime.h>

#define ACT 14
#define CC 128
#define HH 256
#define EPB 182                 // edges per batch (14*13)
#define NB 2048
#define M2 (NB*EPB)             // 372736 edge-rows
#define NS 520                  // nodeL stride in shorts
#define LP_CONST (-182.0f * 0.91893853320467274f)   // -E*0.5*ln(2pi)

typedef short s16x8 __attribute__((ext_vector_type(8)));
typedef _Float16 h16x8 __attribute__((ext_vector_type(8)));
typedef _Float16 h16x2 __attribute__((ext_vector_type(2)));
typedef float f32x2 __attribute__((ext_vector_type(2)));
typedef float f32x4 __attribute__((ext_vector_type(4)));
typedef int   i32x4 __attribute__((ext_vector_type(4)));
typedef float f32x16 __attribute__((ext_vector_type(16)));

__device__ __forceinline__ float softplusf(float x) { return x > 15.f ? x : log1pf(expf(x)); }

__device__ __forceinline__ short f2h(float f) {          // scalar f16, RNE
    _Float16 h = (_Float16)f;
    return __builtin_bit_cast(short, h);
}
__device__ __forceinline__ int pk_f16(float a, float b) { // packed f16, RTZ (1 instr)
    return __builtin_bit_cast(int, __builtin_amdgcn_cvt_pkrtz(a, b));
}
__device__ __forceinline__ int pk_f16_rn(float a, float b) {
    return (int)(unsigned short)f2h(a) | ((int)f2h(b) << 16);
}
__device__ __forceinline__ float fdot2i(int a, int b, float c) {
#if __has_builtin(__builtin_amdgcn_fdot2)
    return __builtin_amdgcn_fdot2(__builtin_bit_cast(h16x2, a),
                                  __builtin_bit_cast(h16x2, b), c, false);
#else
    h16x2 av = __builtin_bit_cast(h16x2, a), bv = __builtin_bit_cast(h16x2, b);
    return c + (float)av[0] * (float)bv[0] + (float)av[1] * (float)bv[1];
#endif
}

// ---------------------------------------------------------------------------
// prep: one-time weight conversions (256 blocks x 256), all-fp16 tables.
//  W2h    [256][256] f16   (lin2_w)
//  W1h    [512][128] f16   ([W1L | W1R] rows)
//  cwPT   [128][64]  f16x2 (conv_w rows, k-pairs packed: row j, pair p)
//  w1sPT  [256][64]  f16x2 (W1L+W1R summed rows, k-pairs packed)
// ---------------------------------------------------------------------------
__global__ __launch_bounds__(256) void prep_kernel(
    const float* __restrict__ conv_w, const float* __restrict__ lin1_w,
    const float* __restrict__ lin2_w,
    short* __restrict__ W2h, short* __restrict__ W1h,
    int* __restrict__ cwPT, int* __restrict__ w1sPT)
{
    int i = blockIdx.x * 256 + threadIdx.x;
    W2h[i] = f2h(lin2_w[i]);
    {
        int n = i >> 7, k = i & 127;
        float v = (n < 256) ? lin1_w[n * 256 + k] : lin1_w[(n - 256) * 256 + 128 + k];
        W1h[i] = f2h(v);
    }
    if (i < 8192) {                     // cwPT[j][p]
        int j = i >> 6, p = i & 63;
        cwPT[i] = pk_f16_rn(conv_w[j * 128 + 2 * p], conv_w[j * 128 + 2 * p + 1]);
    }
    if (i < 16384) {                    // w1sPT[h][p]
        int h = i >> 6, p = i & 63;
        float a0 = lin1_w[h * 256 + 2 * p]     + lin1_w[h * 256 + 128 + 2 * p];
        float a1 = lin1_w[h * 256 + 2 * p + 1] + lin1_w[h * 256 + 128 + 2 * p + 1];
        w1sPT[i] = pk_f16_rn(a0, a1);
    }
}

// ---------------------------------------------------------------------------
// actor: TWO batches per block (1024 blocks), 512 threads = 8 waves.
//  A : stage state f16; ssum -> packed f16 pairs; f32 LDS tables.
//  A2: g via row-major fdot2 streams; w via row-major fdot2 streams.
//  B : node GEMM -> nodeL[2] (u+w | v), 16x16x32 f16 MFMA.
//  C : BARRIER-FREE 12 edge-tiles of 32: each wave builds its own B-fragment
//      in registers from nodeL (2x ds_read_b128 + packed-f16 math per chunk),
//      feeds 32x32x16 f16 MFMA directly. No h1L, no build writes, no
//      intra-loop __syncthreads — waves free-run; LDS atomics accumulate.
// ---------------------------------------------------------------------------
__global__ __launch_bounds__(512, 4) void actor_kernel(
    const float* __restrict__ state, const short* __restrict__ W1h,
    const short* __restrict__ W2h,
    const int* __restrict__ cwPT, const float* __restrict__ conv_b,
    const int* __restrict__ w1sPT, const float* __restrict__ lin1_b,
    const float* __restrict__ lin2_b,
    const float* __restrict__ mu_w, const float* __restrict__ sig_w,
    const float* __restrict__ mu_b, const float* __restrict__ sig_b,
    const float* __restrict__ noise, const int* __restrict__ edges,
    float* __restrict__ out)
{
    __shared__ short stateL[2 * 2560];       // 10240 B, dead after phase B
    __shared__ short nodeL[2 * ACT * NS];    // 29120 B
    __shared__ int   ssP[2][64];             // packed ssum f16 pairs
    __shared__ int   gP[2][64];              // packed g f16 pairs
    __shared__ float wL[2][256];
    __shared__ float b2L[256];               // lin2_b
    __shared__ float muL[256], sgL[256];     // mu_w, sig_w (f32)
    __shared__ float mu_acc[384], sg_acc[384];
    __shared__ float lp_acc[2];

    const int t = threadIdx.x, b = blockIdx.x;
    const int lane = t & 63, ln = lane & 15, q = lane >> 4;
    const int w = t >> 6;                     // wave 0..7
    const int l32 = lane & 31, hf = lane >> 5;

    // ---- phase A ----
    #pragma unroll
    for (int it = 0; it < 2; ++it) {
        int idx = it * 512 + t;
        int bt = idx >> 9, row = (idx >> 5) & 15, c4 = idx & 31;
        int kk = c4 >> 3, k8 = (c4 & 7) * 4;
        int* dst = (int*)&stateL[bt * 2560 + kk * 640 + row * 40 + k8];
        if (row < ACT) {
            f32x4 x = *(const f32x4*)(state + ((size_t)(2 * b + bt) * ACT + row) * CC + c4 * 4);
            dst[0] = pk_f16(x[0], x[1]); dst[1] = pk_f16(x[2], x[3]);
        } else { dst[0] = 0; dst[1] = 0; }
    }
    if (t < 256) {
        b2L[t] = lin2_b[t];
        muL[t] = mu_w[t];
        sgL[t] = sig_w[t];
    } else {
        int i = t - 256, bt = i >> 7, c = i & 127;    // ssum, both batches
        const float* sp = state + (size_t)(2 * b + bt) * ACT * CC + c;
        float s = 0.f;
        #pragma unroll
        for (int r = 0; r < ACT; ++r) s += sp[r * CC];
        s *= (1.f / 14.f);
        float s2 = __shfl_xor(s, 1);          // partner channel (pairs in-wave)
        if (!(c & 1)) ssP[bt][c >> 1] = pk_f16(s, s2);
    }
    if (t < 384) { mu_acc[t] = 0.f; sg_acc[t] = 0.f; }
    if (t < 2) lp_acc[t] = 0.f;
    __syncthreads();

    // ---- phase A2: g = relu(conv_w @ ssum + b), fdot2 row streams ----
    {
        int bt = t >> 8, r = t & 255, j = r >> 1, s = r & 1;
        const i32x4* wp = (const i32x4*)&cwPT[j * 64 + s * 32];
        const i32x4* sp4 = (const i32x4*)&ssP[bt][s * 32];
        float a0 = 0.f, a1 = 0.f, a2 = 0.f, a3 = 0.f;
        #pragma unroll
        for (int u = 0; u < 8; ++u) {
            i32x4 wv = wp[u]; i32x4 sv = sp4[u];
            a0 = fdot2i(wv[0], sv[0], a0); a1 = fdot2i(wv[1], sv[1], a1);
            a2 = fdot2i(wv[2], sv[2], a2); a3 = fdot2i(wv[3], sv[3], a3);
        }
        float a = (a0 + a1) + (a2 + a3);
        a += __shfl_xor(a, 1);                // combine k-split halves
        float gf = fmaxf(a + conv_b[j], 0.f);
        float go = __shfl_xor(gf, 2);         // neighbor j^1
        if ((r & 3) == 0) gP[bt][r >> 2] = pk_f16(gf, go);
    }
    __syncthreads();
    // ---- w = w1s @ g + lin1_b, fdot2 row streams ----
    {
        int bt = t >> 8, h = t & 255;
        const i32x4* wp = (const i32x4*)&w1sPT[h * 64];
        const i32x4* gp4 = (const i32x4*)&gP[bt][0];
        float a0 = 0.f, a1 = 0.f, a2 = 0.f, a3 = 0.f;
        #pragma unroll 8
        for (int u = 0; u < 16; ++u) {
            i32x4 wv = wp[u]; i32x4 gv = gp4[u];
            a0 = fdot2i(wv[0], gv[0], a0); a1 = fdot2i(wv[1], gv[1], a1);
            a2 = fdot2i(wv[2], gv[2], a2); a3 = fdot2i(wv[3], gv[3], a3);
        }
        wL[bt][h] = (a0 + a1) + (a2 + a3) + lin1_b[h];
    }
    __syncthreads();

    // ---- phase B: node GEMM (u = W1L@x + w | v = W1R@x), both batches ----
    f32x4 zero4 = {0.f, 0.f, 0.f, 0.f};
    f32x4 nacc[2][4];
    #pragma unroll
    for (int bt = 0; bt < 2; ++bt) {
        nacc[bt][0] = zero4; nacc[bt][1] = zero4;
        nacc[bt][2] = zero4; nacc[bt][3] = zero4;
    }
    #pragma unroll
    for (int c = 0; c < 4; ++c) {
        h16x8 a80 = __builtin_bit_cast(h16x8, *(const s16x8*)&stateL[0 * 2560 + c * 640 + ln * 40 + q * 8]);
        h16x8 a81 = __builtin_bit_cast(h16x8, *(const s16x8*)&stateL[1 * 2560 + c * 640 + ln * 40 + q * 8]);
        #pragma unroll
        for (int i = 0; i < 4; ++i) {
            int ct = w + 8 * i;               // 0..31
            h16x8 b8 = __builtin_bit_cast(h16x8, *(const s16x8*)&W1h[(size_t)(ct * 16 + ln) * CC + c * 32 + q * 8]);
            nacc[0][i] = __builtin_amdgcn_mfma_f32_16x16x32_f16(a80, b8, nacc[0][i], 0, 0, 0);
            nacc[1][i] = __builtin_amdgcn_mfma_f32_16x16x32_f16(a81, b8, nacc[1][i], 0, 0, 0);
        }
    }
    #pragma unroll
    for (int bt = 0; bt < 2; ++bt)
        #pragma unroll
        for (int i = 0; i < 4; ++i) {
            int col = (w + 8 * i) * 16 + ln;
            float wadd = (col < HH) ? wL[bt][col] : 0.f;
            #pragma unroll
            for (int rg = 0; rg < 4; ++rg) {
                int node = q * 4 + rg;
                if (node < ACT) nodeL[(bt * ACT + node) * NS + col] = f2h(nacc[bt][i][rg] + wadd);
            }
        }

    // ---- W2 strip (32 rows x K=256) into VGPRs ----
    s16x8 wa[16];
    #pragma unroll
    for (int c = 0; c < 16; ++c)
        wa[c] = *(const s16x8*)&W2h[(size_t)(w * 32 + l32) * HH + c * 16 + hf * 8];
    __syncthreads();   // nodeL visible to all waves; no more block barriers until head

    // ---- phase C: barrier-free edge tiles, per-wave register-built B-frags
    const h16x2 c001 = {(_Float16)0.01f, (_Float16)0.01f};
    const f32x2 c001p = {0.01f, 0.01f};
    for (int tile = 0; tile < 12; ++tile) {
        const int bt = (tile >= 6) ? 1 : 0;
        const int col0 = (tile - bt * 6) * 32;
        int e = col0 + l32;
        if (e > EPB - 1) e = EPB - 1;          // ragged tail: junk cols unread
        int2 p = ((const int2*)edges)[e];
        const int base = bt * ACT * NS;
        const int uo = base + p.x * NS + hf * 8;
        const int vo = base + HH + p.y * NS + hf * 8;

        f32x16 acc;
        #pragma unroll
        for (int r = 0; r < 16; ++r) acc[r] = 0.f;
        #pragma unroll
        for (int c = 0; c < 16; ++c) {
            s16x8 u8 = *(const s16x8*)&nodeL[uo + c * 16];
            s16x8 v8 = *(const s16x8*)&nodeL[vo + c * 16];
            const int* ui = (const int*)&u8;
            const int* vi = (const int*)&v8;
            i32x4 o;
            #pragma unroll
            for (int j = 0; j < 4; ++j) {
                h16x2 uu = __builtin_bit_cast(h16x2, ui[j]);
                h16x2 vv = __builtin_bit_cast(h16x2, vi[j]);
                h16x2 sum = uu + vv;
                h16x2 lk  = __builtin_elementwise_max(sum, sum * c001);
                o[j] = __builtin_bit_cast(int, lk);
            }
            h16x8 b8 = __builtin_bit_cast(h16x8, o);
            h16x8 a8 = __builtin_bit_cast(h16x8, wa[c]);
            acc = __builtin_amdgcn_mfma_f32_32x32x16_f16(a8, b8, acc, 0, 0, 0);
        }
        // packed-f32 epilogue: lane&31 = edge; regs r: n = w*32 + 4hf + 8g + i
        f32x2 pm = {0.f, 0.f}, ps = {0.f, 0.f};
        const int nsb = w * 32 + 4 * hf;
        #pragma unroll
        for (int g = 0; g < 4; ++g) {
            f32x4 b4 = *(const f32x4*)&b2L[nsb + 8 * g];
            f32x4 m4 = *(const f32x4*)&muL[nsb + 8 * g];
            f32x4 s4 = *(const f32x4*)&sgL[nsb + 8 * g];
            #pragma unroll
            for (int pp = 0; pp < 2; ++pp) {
                f32x2 a2 = {acc[g * 4 + 2 * pp], acc[g * 4 + 2 * pp + 1]};
                f32x2 b2 = {b4[2 * pp], b4[2 * pp + 1]};
                f32x2 x  = a2 + b2;
                f32x2 lk = __builtin_elementwise_max(x, x * c001p);
                f32x2 mm = {m4[2 * pp], m4[2 * pp + 1]};
                f32x2 sv = {s4[2 * pp], s4[2 * pp + 1]};
                pm += mm * lk;
                ps += sv * lk;
            }
        }
        float pmu = pm[0] + pm[1];
        float psg = ps[0] + ps[1];
        pmu += __shfl_xor(pmu, 32);
        psg += __shfl_xor(psg, 32);
        if (lane < 32) atomicAdd(&mu_acc[bt * 192 + col0 + l32], pmu);
        else           atomicAdd(&sg_acc[bt * 192 + col0 + l32], psg);
    }
    __syncthreads();

    // ---- final head, both batches ----
    float lpv = 0.f;
    {
        int bt = t >> 8, i = t & 255;
        if (i < EPB) {
            float mu = softplusf(mu_acc[bt * 192 + i] + mu_b[0]);
            float sd = softplusf(sg_acc[bt * 192 + i] + sig_b[0]);
            float z = noise[(size_t)(2 * b + bt) * EPB + i];
            out[(size_t)(2 * b + bt) * EPB + i] = mu + sd * z;
            lpv = -0.5f * z * z - logf(sd);
        }
    }
    #pragma unroll
    for (int off = 1; off < 64; off <<= 1) lpv += __shfl_xor(lpv, off);
    if (lane == 0) atomicAdd(&lp_acc[t >> 8], lpv);
    __syncthreads();
    if (t < 2) out[M2 + 2 * b + t] = lp_acc[t] + LP_CONST;
}

// ---------------------------------------------------------------------------
extern "C" void kernel_launch(void* const* d_in, const int* in_sizes, int n_in,
                              void* d_out, int out_size, void* d_ws, size_t ws_size,
                              hipStream_t stream)
{
    const float* state  = (const float*)d_in[0];
    const float* conv_w = (const float*)d_in[1];
    const float* conv_b = (const float*)d_in[2];
    const float* lin1_w = (const float*)d_in[3];
    const float* lin1_b = (const float*)d_in[4];
    const float* lin2_w = (const float*)d_in[5];
    const float* lin2_b = (const float*)d_in[6];
    const float* mu_w   = (const float*)d_in[7];
    const float* mu_b   = (const float*)d_in[8];
    const float* sig_w  = (const float*)d_in[9];
    const float* sig_b  = (const float*)d_in[10];
    const float* noise  = (const float*)d_in[11];
    const int*   edges  = (const int*)d_in[13];
    float* out = (float*)d_out;

    char* ws = (char*)d_ws;
    short* W2h    = (short*)ws;  ws += 65536 * 2;
    short* W1h    = (short*)ws;  ws += 65536 * 2;
    int*   cwPT   = (int*)ws;    ws += 8192 * 4;
    int*   w1sPT  = (int*)ws;    ws += 16384 * 4;

    prep_kernel<<<256, 256, 0, stream>>>(conv_w, lin1_w, lin2_w,
                                         W2h, W1h, cwPT, w1sPT);
    actor_kernel<<<NB / 2, 512, 0, stream>>>(state, W1h, W2h,
                                             cwPT, conv_b, w1sPT, lin1_b,
                                             lin2_b, mu_w, sig_w, mu_b, sig_b,
                                             noise, edges, out);
}

// Round 7
// 204.028 us; speedup vs baseline: 1.1540x; 1.1540x over previous
//
#include <hip/hip_runtime.h>

#define ACT 14
#define CC 128
#define HH 256
#define EPB 182                 // edges per batch (14*13)
#define NB 2048
#define M2 (NB*EPB)             // 372736 edge-rows
#define NS 520                  // nodeL stride in shorts
#define LP_CONST (-182.0f * 0.91893853320467274f)   // -E*0.5*ln(2pi)

typedef short s16x8 __attribute__((ext_vector_type(8)));
typedef _Float16 h16x8 __attribute__((ext_vector_type(8)));
typedef _Float16 h16x2 __attribute__((ext_vector_type(2)));
typedef float f32x2 __attribute__((ext_vector_type(2)));
typedef float f32x4 __attribute__((ext_vector_type(4)));
typedef int   i32x4 __attribute__((ext_vector_type(4)));
typedef float f32x16 __attribute__((ext_vector_type(16)));

__device__ __forceinline__ float softplusf(float x) { return x > 15.f ? x : log1pf(expf(x)); }

__device__ __forceinline__ short f2h(float f) {          // scalar f16, RNE
    _Float16 h = (_Float16)f;
    return __builtin_bit_cast(short, h);
}
__device__ __forceinline__ int pk_f16(float a, float b) { // packed f16, RTZ (1 instr)
    return __builtin_bit_cast(int, __builtin_amdgcn_cvt_pkrtz(a, b));
}
__device__ __forceinline__ int pk_f16_rn(float a, float b) {
    return (int)(unsigned short)f2h(a) | ((int)f2h(b) << 16);
}
__device__ __forceinline__ float fdot2i(int a, int b, float c) {
#if __has_builtin(__builtin_amdgcn_fdot2)
    return __builtin_amdgcn_fdot2(__builtin_bit_cast(h16x2, a),
                                  __builtin_bit_cast(h16x2, b), c, false);
#else
    h16x2 av = __builtin_bit_cast(h16x2, a), bv = __builtin_bit_cast(h16x2, b);
    return c + (float)av[0] * (float)bv[0] + (float)av[1] * (float)bv[1];
#endif
}

// ---------------------------------------------------------------------------
// prep: one-time weight conversions (256 blocks x 256), all-fp16 tables.
//  W2h    [256][256] f16   (lin2_w)
//  W1h    [512][128] f16   ([W1L | W1R] rows)
//  cwPT   [128][64]  f16x2 (conv_w rows, k-pairs packed: row j, pair p)
//  w1sPT  [256][64]  f16x2 (W1L+W1R summed rows, k-pairs packed)
// ---------------------------------------------------------------------------
__global__ __launch_bounds__(256) void prep_kernel(
    const float* __restrict__ conv_w, const float* __restrict__ lin1_w,
    const float* __restrict__ lin2_w,
    short* __restrict__ W2h, short* __restrict__ W1h,
    int* __restrict__ cwPT, int* __restrict__ w1sPT)
{
    int i = blockIdx.x * 256 + threadIdx.x;
    W2h[i] = f2h(lin2_w[i]);
    {
        int n = i >> 7, k = i & 127;
        float v = (n < 256) ? lin1_w[n * 256 + k] : lin1_w[(n - 256) * 256 + 128 + k];
        W1h[i] = f2h(v);
    }
    if (i < 8192) {                     // cwPT[j][p]
        int j = i >> 6, p = i & 63;
        cwPT[i] = pk_f16_rn(conv_w[j * 128 + 2 * p], conv_w[j * 128 + 2 * p + 1]);
    }
    if (i < 16384) {                    // w1sPT[h][p]
        int h = i >> 6, p = i & 63;
        float a0 = lin1_w[h * 256 + 2 * p]     + lin1_w[h * 256 + 128 + 2 * p];
        float a1 = lin1_w[h * 256 + 2 * p + 1] + lin1_w[h * 256 + 128 + 2 * p + 1];
        w1sPT[i] = pk_f16_rn(a0, a1);
    }
}

// ---------------------------------------------------------------------------
// actor: TWO batches per block (1024 blocks), 512 threads = 8 waves.
//  A : stage state f16; ssum -> packed f16 pairs; f32 LDS tables.
//  A2: g via row-major fdot2 streams; w via row-major fdot2 streams.
//  B : node GEMM -> nodeL[2] (u+w | v), 16x16x32 f16 MFMA.
//  C : BARRIER-FREE 12 edge-tiles of 32: per-wave register-built B-frags
//      from nodeL with a 1-deep load pipeline + sched_barrier(0) fences
//      (bounds the ds_read live-range -> no spill). 32x32x16 f16 MFMA.
//      No intra-loop __syncthreads; LDS atomics accumulate.
// ---------------------------------------------------------------------------
__global__ __launch_bounds__(512, 4) void actor_kernel(
    const float* __restrict__ state, const short* __restrict__ W1h,
    const short* __restrict__ W2h,
    const int* __restrict__ cwPT, const float* __restrict__ conv_b,
    const int* __restrict__ w1sPT, const float* __restrict__ lin1_b,
    const float* __restrict__ lin2_b,
    const float* __restrict__ mu_w, const float* __restrict__ sig_w,
    const float* __restrict__ mu_b, const float* __restrict__ sig_b,
    const float* __restrict__ noise, const int* __restrict__ edges,
    float* __restrict__ out)
{
    __shared__ short stateL[2 * 2560];       // 10240 B, dead after phase B
    __shared__ short nodeL[2 * ACT * NS];    // 29120 B
    __shared__ int   ssP[2][64];             // packed ssum f16 pairs
    __shared__ int   gP[2][64];              // packed g f16 pairs
    __shared__ float wL[2][256];
    __shared__ float b2L[256];               // lin2_b
    __shared__ float muL[256], sgL[256];     // mu_w, sig_w (f32)
    __shared__ float mu_acc[384], sg_acc[384];
    __shared__ float lp_acc[2];

    const int t = threadIdx.x, b = blockIdx.x;
    const int lane = t & 63, ln = lane & 15, q = lane >> 4;
    const int w = t >> 6;                     // wave 0..7
    const int l32 = lane & 31, hf = lane >> 5;

    // ---- phase A ----
    #pragma unroll
    for (int it = 0; it < 2; ++it) {
        int idx = it * 512 + t;
        int bt = idx >> 9, row = (idx >> 5) & 15, c4 = idx & 31;
        int kk = c4 >> 3, k8 = (c4 & 7) * 4;
        int* dst = (int*)&stateL[bt * 2560 + kk * 640 + row * 40 + k8];
        if (row < ACT) {
            f32x4 x = *(const f32x4*)(state + ((size_t)(2 * b + bt) * ACT + row) * CC + c4 * 4);
            dst[0] = pk_f16(x[0], x[1]); dst[1] = pk_f16(x[2], x[3]);
        } else { dst[0] = 0; dst[1] = 0; }
    }
    if (t < 256) {
        b2L[t] = lin2_b[t];
        muL[t] = mu_w[t];
        sgL[t] = sig_w[t];
    } else {
        int i = t - 256, bt = i >> 7, c = i & 127;    // ssum, both batches
        const float* sp = state + (size_t)(2 * b + bt) * ACT * CC + c;
        float s = 0.f;
        #pragma unroll
        for (int r = 0; r < ACT; ++r) s += sp[r * CC];
        s *= (1.f / 14.f);
        float s2 = __shfl_xor(s, 1);          // partner channel (pairs in-wave)
        if (!(c & 1)) ssP[bt][c >> 1] = pk_f16(s, s2);
    }
    if (t < 384) { mu_acc[t] = 0.f; sg_acc[t] = 0.f; }
    if (t < 2) lp_acc[t] = 0.f;
    __syncthreads();

    // ---- phase A2: g = relu(conv_w @ ssum + b), fdot2 row streams ----
    {
        int bt = t >> 8, r = t & 255, j = r >> 1, s = r & 1;
        const i32x4* wp = (const i32x4*)&cwPT[j * 64 + s * 32];
        const i32x4* sp4 = (const i32x4*)&ssP[bt][s * 32];
        float a0 = 0.f, a1 = 0.f, a2 = 0.f, a3 = 0.f;
        #pragma unroll
        for (int u = 0; u < 8; ++u) {
            i32x4 wv = wp[u]; i32x4 sv = sp4[u];
            a0 = fdot2i(wv[0], sv[0], a0); a1 = fdot2i(wv[1], sv[1], a1);
            a2 = fdot2i(wv[2], sv[2], a2); a3 = fdot2i(wv[3], sv[3], a3);
        }
        float a = (a0 + a1) + (a2 + a3);
        a += __shfl_xor(a, 1);                // combine k-split halves
        float gf = fmaxf(a + conv_b[j], 0.f);
        float go = __shfl_xor(gf, 2);         // neighbor j^1
        if ((r & 3) == 0) gP[bt][r >> 2] = pk_f16(gf, go);
    }
    __syncthreads();
    // ---- w = w1s @ g + lin1_b, fdot2 row streams ----
    {
        int bt = t >> 8, h = t & 255;
        const i32x4* wp = (const i32x4*)&w1sPT[h * 64];
        const i32x4* gp4 = (const i32x4*)&gP[bt][0];
        float a0 = 0.f, a1 = 0.f, a2 = 0.f, a3 = 0.f;
        #pragma unroll 8
        for (int u = 0; u < 16; ++u) {
            i32x4 wv = wp[u]; i32x4 gv = gp4[u];
            a0 = fdot2i(wv[0], gv[0], a0); a1 = fdot2i(wv[1], gv[1], a1);
            a2 = fdot2i(wv[2], gv[2], a2); a3 = fdot2i(wv[3], gv[3], a3);
        }
        wL[bt][h] = (a0 + a1) + (a2 + a3) + lin1_b[h];
    }
    __syncthreads();

    // ---- phase B: node GEMM (u = W1L@x + w | v = W1R@x), both batches ----
    f32x4 zero4 = {0.f, 0.f, 0.f, 0.f};
    f32x4 nacc[2][4];
    #pragma unroll
    for (int bt = 0; bt < 2; ++bt) {
        nacc[bt][0] = zero4; nacc[bt][1] = zero4;
        nacc[bt][2] = zero4; nacc[bt][3] = zero4;
    }
    #pragma unroll
    for (int c = 0; c < 4; ++c) {
        h16x8 a80 = __builtin_bit_cast(h16x8, *(const s16x8*)&stateL[0 * 2560 + c * 640 + ln * 40 + q * 8]);
        h16x8 a81 = __builtin_bit_cast(h16x8, *(const s16x8*)&stateL[1 * 2560 + c * 640 + ln * 40 + q * 8]);
        #pragma unroll
        for (int i = 0; i < 4; ++i) {
            int ct = w + 8 * i;               // 0..31
            h16x8 b8 = __builtin_bit_cast(h16x8, *(const s16x8*)&W1h[(size_t)(ct * 16 + ln) * CC + c * 32 + q * 8]);
            nacc[0][i] = __builtin_amdgcn_mfma_f32_16x16x32_f16(a80, b8, nacc[0][i], 0, 0, 0);
            nacc[1][i] = __builtin_amdgcn_mfma_f32_16x16x32_f16(a81, b8, nacc[1][i], 0, 0, 0);
        }
    }
    #pragma unroll
    for (int bt = 0; bt < 2; ++bt)
        #pragma unroll
        for (int i = 0; i < 4; ++i) {
            int col = (w + 8 * i) * 16 + ln;
            float wadd = (col < HH) ? wL[bt][col] : 0.f;
            #pragma unroll
            for (int rg = 0; rg < 4; ++rg) {
                int node = q * 4 + rg;
                if (node < ACT) nodeL[(bt * ACT + node) * NS + col] = f2h(nacc[bt][i][rg] + wadd);
            }
        }

    // ---- W2 strip (32 rows x K=256) into VGPRs ----
    s16x8 wa[16];
    #pragma unroll
    for (int c = 0; c < 16; ++c)
        wa[c] = *(const s16x8*)&W2h[(size_t)(w * 32 + l32) * HH + c * 16 + hf * 8];
    __syncthreads();   // nodeL visible to all waves; no more block barriers until head

    // ---- phase C: barrier-free edge tiles, per-wave register-built B-frags,
    //      1-deep ds_read pipeline + sched_barrier(0) fences (no spill)
    const h16x2 c001 = {(_Float16)0.01f, (_Float16)0.01f};
    const f32x2 c001p = {0.01f, 0.01f};
    for (int tile = 0; tile < 12; ++tile) {
        const int bt = (tile >= 6) ? 1 : 0;
        const int col0 = (tile - bt * 6) * 32;
        int e = col0 + l32;
        if (e > EPB - 1) e = EPB - 1;          // ragged tail: junk cols unread
        int2 p = ((const int2*)edges)[e];
        const int base = bt * ACT * NS;
        const int uo = base + p.x * NS + hf * 8;
        const int vo = base + HH + p.y * NS + hf * 8;

        f32x16 acc;
        #pragma unroll
        for (int r = 0; r < 16; ++r) acc[r] = 0.f;

        s16x8 u8 = *(const s16x8*)&nodeL[uo];
        s16x8 v8 = *(const s16x8*)&nodeL[vo];
        #pragma unroll
        for (int c = 0; c < 16; ++c) {
            const int* ui = (const int*)&u8;
            const int* vi = (const int*)&v8;
            i32x4 o;
            #pragma unroll
            for (int j = 0; j < 4; ++j) {
                h16x2 uu = __builtin_bit_cast(h16x2, ui[j]);
                h16x2 vv = __builtin_bit_cast(h16x2, vi[j]);
                h16x2 sum = uu + vv;
                h16x2 lk  = __builtin_elementwise_max(sum, sum * c001);
                o[j] = __builtin_bit_cast(int, lk);
            }
            s16x8 un, vn;
            if (c < 15) {
                un = *(const s16x8*)&nodeL[uo + (c + 1) * 16];
                vn = *(const s16x8*)&nodeL[vo + (c + 1) * 16];
            }
            h16x8 b8 = __builtin_bit_cast(h16x8, o);
            h16x8 a8 = __builtin_bit_cast(h16x8, wa[c]);
            acc = __builtin_amdgcn_mfma_f32_32x32x16_f16(a8, b8, acc, 0, 0, 0);
            __builtin_amdgcn_sched_barrier(0);   // bound live-range: <=1 chunk ahead
            if (c < 15) { u8 = un; v8 = vn; }
        }
        // packed-f32 epilogue: lane&31 = edge; regs r: n = w*32 + 4hf + 8g + i
        f32x2 pm = {0.f, 0.f}, ps = {0.f, 0.f};
        const int nsb = w * 32 + 4 * hf;
        #pragma unroll
        for (int g = 0; g < 4; ++g) {
            f32x4 b4 = *(const f32x4*)&b2L[nsb + 8 * g];
            f32x4 m4 = *(const f32x4*)&muL[nsb + 8 * g];
            f32x4 s4 = *(const f32x4*)&sgL[nsb + 8 * g];
            #pragma unroll
            for (int pp = 0; pp < 2; ++pp) {
                f32x2 a2 = {acc[g * 4 + 2 * pp], acc[g * 4 + 2 * pp + 1]};
                f32x2 b2 = {b4[2 * pp], b4[2 * pp + 1]};
                f32x2 x  = a2 + b2;
                f32x2 lk = __builtin_elementwise_max(x, x * c001p);
                f32x2 mm = {m4[2 * pp], m4[2 * pp + 1]};
                f32x2 sv = {s4[2 * pp], s4[2 * pp + 1]};
                pm += mm * lk;
                ps += sv * lk;
            }
        }
        float pmu = pm[0] + pm[1];
        float psg = ps[0] + ps[1];
        pmu += __shfl_xor(pmu, 32);
        psg += __shfl_xor(psg, 32);
        if (lane < 32) atomicAdd(&mu_acc[bt * 192 + col0 + l32], pmu);
        else           atomicAdd(&sg_acc[bt * 192 + col0 + l32], psg);
    }
    __syncthreads();

    // ---- final head, both batches ----
    float lpv = 0.f;
    {
        int bt = t >> 8, i = t & 255;
        if (i < EPB) {
            float mu = softplusf(mu_acc[bt * 192 + i] + mu_b[0]);
            float sd = softplusf(sg_acc[bt * 192 + i] + sig_b[0]);
            float z = noise[(size_t)(2 * b + bt) * EPB + i];
            out[(size_t)(2 * b + bt) * EPB + i] = mu + sd * z;
            lpv = -0.5f * z * z - logf(sd);
        }
    }
    #pragma unroll
    for (int off = 1; off < 64; off <<= 1) lpv += __shfl_xor(lpv, off);
    if (lane == 0) atomicAdd(&lp_acc[t >> 8], lpv);
    __syncthreads();
    if (t < 2) out[M2 + 2 * b + t] = lp_acc[t] + LP_CONST;
}

// ---------------------------------------------------------------------------
extern "C" void kernel_launch(void* const* d_in, const int* in_sizes, int n_in,
                              void* d_out, int out_size, void* d_ws, size_t ws_size,
                              hipStream_t stream)
{
    const float* state  = (const float*)d_in[0];
    const float* conv_w = (const float*)d_in[1];
    const float* conv_b = (const float*)d_in[2];
    const float* lin1_w = (const float*)d_in[3];
    const float* lin1_b = (const float*)d_in[4];
    const float* lin2_w = (const float*)d_in[5];
    const float* lin2_b = (const float*)d_in[6];
    const float* mu_w   = (const float*)d_in[7];
    const float* mu_b   = (const float*)d_in[8];
    const float* sig_w  = (const float*)d_in[9];
    const float* sig_b  = (const float*)d_in[10];
    const float* noise  = (const float*)d_in[11];
    const int*   edges  = (const int*)d_in[13];
    float* out = (float*)d_out;

    char* ws = (char*)d_ws;
    short* W2h    = (short*)ws;  ws += 65536 * 2;
    short* W1h    = (short*)ws;  ws += 65536 * 2;
    int*   cwPT   = (int*)ws;    ws += 8192 * 4;
    int*   w1sPT  = (int*)ws;    ws += 16384 * 4;

    prep_kernel<<<256, 256, 0, stream>>>(conv_w, lin1_w, lin2_w,
                                         W2h, W1h, cwPT, w1sPT);
    actor_kernel<<<NB / 2, 512, 0, stream>>>(state, W1h, W2h,
                                             cwPT, conv_b, w1sPT, lin1_b,
                                             lin2_b, mu_w, sig_w, mu_b, sig_b,
                                             noise, edges, out);
}

// Round 8
// 199.563 us; speedup vs baseline: 1.1798x; 1.0224x over previous
//
#include <hip/hip_runtime.h>

#define ACT 14
#define CC 128
#define HH 256
#define EPB 182                 // edges per batch (14*13)
#define NB 2048
#define M2 (NB*EPB)             // 372736 edge-rows
#define NS 520                  // nodeL stride in shorts
#define LP_CONST (-182.0f * 0.91893853320467274f)   // -E*0.5*ln(2pi)

typedef short s16x8 __attribute__((ext_vector_type(8)));
typedef _Float16 h16x8 __attribute__((ext_vector_type(8)));
typedef _Float16 h16x2 __attribute__((ext_vector_type(2)));
typedef float f32x2 __attribute__((ext_vector_type(2)));
typedef float f32x4 __attribute__((ext_vector_type(4)));
typedef int   i32x4 __attribute__((ext_vector_type(4)));
typedef float f32x16 __attribute__((ext_vector_type(16)));

__device__ __forceinline__ float softplusf(float x) { return x > 15.f ? x : log1pf(expf(x)); }
__device__ __forceinline__ float leaky(float x) { return fmaxf(x, 0.01f * x); }

__device__ __forceinline__ short f2bf(float f) {
    unsigned u = __float_as_uint(f);
    unsigned r = (u + 0x7fffu + ((u >> 16) & 1u)) >> 16;   // RNE
    return (short)r;
}
__device__ __forceinline__ float bflo(int m) { return __uint_as_float(((unsigned)m) << 16); }
__device__ __forceinline__ float bfhi(int m) { return __uint_as_float((unsigned)m & 0xffff0000u); }

__device__ __forceinline__ short f2h(float f) {          // scalar f16, RNE
    _Float16 h = (_Float16)f;
    return __builtin_bit_cast(short, h);
}
__device__ __forceinline__ int pk_f16(float a, float b) { // packed f16, RTZ (1 instr)
    return __builtin_bit_cast(int, __builtin_amdgcn_cvt_pkrtz(a, b));
}
__device__ __forceinline__ int pk_f16_rn(float a, float b) {
    return (int)(unsigned short)f2h(a) | ((int)f2h(b) << 16);
}
__device__ __forceinline__ float fdot2i(int a, int b, float c) {
#if __has_builtin(__builtin_amdgcn_fdot2)
    return __builtin_amdgcn_fdot2(__builtin_bit_cast(h16x2, a),
                                  __builtin_bit_cast(h16x2, b), c, false);
#else
    h16x2 av = __builtin_bit_cast(h16x2, a), bv = __builtin_bit_cast(h16x2, b);
    return c + (float)av[0] * (float)bv[0] + (float)av[1] * (float)bv[1];
#endif
}

// ---------------------------------------------------------------------------
// prep: one-time weight conversions (256 blocks x 256), fp16 tables.
//  W2h    [256][256] f16   (lin2_w)
//  W1h    [512][128] f16   ([W1L | W1R] rows)
//  cwPT   [128][64]  f16x2 (conv_w rows, k-pairs packed)
//  w1sPT  [256][64]  f16x2 (W1L+W1R summed rows, k-pairs packed)
//  msbf   [256]      bf16x2 ((mu_w, sig_w) pairs)
// ---------------------------------------------------------------------------
__global__ __launch_bounds__(256) void prep_kernel(
    const float* __restrict__ conv_w, const float* __restrict__ lin1_w,
    const float* __restrict__ lin2_w, const float* __restrict__ mu_w,
    const float* __restrict__ sig_w,
    short* __restrict__ W2h, short* __restrict__ W1h,
    int* __restrict__ cwPT, int* __restrict__ w1sPT,
    int* __restrict__ msbf)
{
    int i = blockIdx.x * 256 + threadIdx.x;
    W2h[i] = f2h(lin2_w[i]);
    {
        int n = i >> 7, k = i & 127;
        float v = (n < 256) ? lin1_w[n * 256 + k] : lin1_w[(n - 256) * 256 + 128 + k];
        W1h[i] = f2h(v);
    }
    if (i < 8192) {                     // cwPT[j][p]
        int j = i >> 6, p = i & 63;
        cwPT[i] = pk_f16_rn(conv_w[j * 128 + 2 * p], conv_w[j * 128 + 2 * p + 1]);
    }
    if (i < 16384) {                    // w1sPT[h][p]
        int h = i >> 6, p = i & 63;
        float a0 = lin1_w[h * 256 + 2 * p]     + lin1_w[h * 256 + 128 + 2 * p];
        float a1 = lin1_w[h * 256 + 2 * p + 1] + lin1_w[h * 256 + 128 + 2 * p + 1];
        w1sPT[i] = pk_f16_rn(a0, a1);
    }
    if (i < 256) msbf[i] = (int)(unsigned short)f2bf(mu_w[i]) | ((int)f2bf(sig_w[i]) << 16);
}

// ---------------------------------------------------------------------------
// actor: TWO batches per block (1024 blocks), 512 threads = 8 waves.
//  A : stage state f16 (aliased into h1L); ssum -> packed pairs; LDS tables
//      incl. edgeL (kills per-tile unhidden global edge loads).
//  A2: g via fdot2 row streams + shfl; w via fdot2 row streams.
//  B : node GEMM -> nodeL[2], 16x16x32 f16 MFMA; wa (W2 strip) global loads
//      issued between MFMA loop and nodeL writes (latency hidden by
//      writes+barrier, reg peak ~105 < 128 -> no spill).
//  C : cooperative double-buffered H1 build (LDS-cheapest structure: 6 build
//      + 16 frag + 8 packed-epilogue ops/tile/wave), 32x32x16 f16 MFMA,
//      packed-bf16 mu/sig epilogue, split-halves LDS atomics.
// ---------------------------------------------------------------------------
__global__ __launch_bounds__(512, 4) void actor_kernel(
    const float* __restrict__ state, const short* __restrict__ W1h,
    const short* __restrict__ W2h,
    const int* __restrict__ cwPT, const float* __restrict__ conv_b,
    const int* __restrict__ w1sPT, const float* __restrict__ lin1_b,
    const float* __restrict__ lin2_b, const int* __restrict__ msbf,
    const float* __restrict__ mu_b, const float* __restrict__ sig_b,
    const float* __restrict__ noise, const int* __restrict__ edges,
    float* __restrict__ out)
{
    __shared__ short h1L[2][8192];           // 32 KB; [0] front aliased below
    __shared__ short nodeL[2 * ACT * NS];    // 29120 B
    __shared__ int   ssP[2][64];             // packed ssum f16 pairs
    __shared__ int   gP[2][64];              // packed g f16 pairs
    __shared__ float wL[2][256];
    __shared__ float b2L[256];               // lin2_b (f32)
    __shared__ int   msL[256];               // packed (mu,sig) bf16 pairs
    __shared__ int2  edgeL[192];             // edge pairs (182 used)
    __shared__ float mu_acc[384], sg_acc[384];
    __shared__ float lp_acc[2];

    short* stateL = &h1L[0][0];              // 2*2560 shorts (dead before build)

    const int t = threadIdx.x, b = blockIdx.x;
    const int lane = t & 63, ln = lane & 15, q = lane >> 4;
    const int w = t >> 6;                     // wave 0..7
    const int l32 = lane & 31, hf = lane >> 5;

    // ---- phase A ----
    #pragma unroll
    for (int it = 0; it < 2; ++it) {
        int idx = it * 512 + t;
        int bt = idx >> 9, row = (idx >> 5) & 15, c4 = idx & 31;
        int kk = c4 >> 3, k8 = (c4 & 7) * 4;
        int* dst = (int*)&stateL[bt * 2560 + kk * 640 + row * 40 + k8];
        if (row < ACT) {
            f32x4 x = *(const f32x4*)(state + ((size_t)(2 * b + bt) * ACT + row) * CC + c4 * 4);
            dst[0] = pk_f16(x[0], x[1]); dst[1] = pk_f16(x[2], x[3]);
        } else { dst[0] = 0; dst[1] = 0; }
    }
    if (t < 256) {
        b2L[t] = lin2_b[t];
        msL[t] = msbf[t];
    } else {
        int i = t - 256, bt = i >> 7, c = i & 127;    // ssum, both batches
        const float* sp = state + (size_t)(2 * b + bt) * ACT * CC + c;
        float s = 0.f;
        #pragma unroll
        for (int r = 0; r < ACT; ++r) s += sp[r * CC];
        s *= (1.f / 14.f);
        float s2 = __shfl_xor(s, 1);          // partner channel (pairs in-wave)
        if (!(c & 1)) ssP[bt][c >> 1] = pk_f16(s, s2);
    }
    if (t < EPB) edgeL[t] = ((const int2*)edges)[t];
    if (t < 384) { mu_acc[t] = 0.f; sg_acc[t] = 0.f; }
    if (t < 2) lp_acc[t] = 0.f;
    __syncthreads();

    // ---- phase A2: g = relu(conv_w @ ssum + b), fdot2 row streams ----
    {
        int bt = t >> 8, r = t & 255, j = r >> 1, s = r & 1;
        const i32x4* wp = (const i32x4*)&cwPT[j * 64 + s * 32];
        const i32x4* sp4 = (const i32x4*)&ssP[bt][s * 32];
        float a0 = 0.f, a1 = 0.f, a2 = 0.f, a3 = 0.f;
        #pragma unroll
        for (int u = 0; u < 8; ++u) {
            i32x4 wv = wp[u]; i32x4 sv = sp4[u];
            a0 = fdot2i(wv[0], sv[0], a0); a1 = fdot2i(wv[1], sv[1], a1);
            a2 = fdot2i(wv[2], sv[2], a2); a3 = fdot2i(wv[3], sv[3], a3);
        }
        float a = (a0 + a1) + (a2 + a3);
        a += __shfl_xor(a, 1);                // combine k-split halves
        float gf = fmaxf(a + conv_b[j], 0.f);
        float go = __shfl_xor(gf, 2);         // neighbor j^1
        if ((r & 3) == 0) gP[bt][r >> 2] = pk_f16(gf, go);
    }
    __syncthreads();
    // ---- w = w1s @ g + lin1_b, fdot2 row streams ----
    {
        int bt = t >> 8, h = t & 255;
        const i32x4* wp = (const i32x4*)&w1sPT[h * 64];
        const i32x4* gp4 = (const i32x4*)&gP[bt][0];
        float a0 = 0.f, a1 = 0.f, a2 = 0.f, a3 = 0.f;
        #pragma unroll 8
        for (int u = 0; u < 16; ++u) {
            i32x4 wv = wp[u]; i32x4 gv = gp4[u];
            a0 = fdot2i(wv[0], gv[0], a0); a1 = fdot2i(wv[1], gv[1], a1);
            a2 = fdot2i(wv[2], gv[2], a2); a3 = fdot2i(wv[3], gv[3], a3);
        }
        wL[bt][h] = (a0 + a1) + (a2 + a3) + lin1_b[h];
    }
    __syncthreads();

    // ---- phase B: node GEMM (u = W1L@x + w | v = W1R@x), both batches ----
    f32x4 zero4 = {0.f, 0.f, 0.f, 0.f};
    f32x4 nacc[2][4];
    #pragma unroll
    for (int bt = 0; bt < 2; ++bt) {
        nacc[bt][0] = zero4; nacc[bt][1] = zero4;
        nacc[bt][2] = zero4; nacc[bt][3] = zero4;
    }
    #pragma unroll
    for (int c = 0; c < 4; ++c) {
        h16x8 a80 = __builtin_bit_cast(h16x8, *(const s16x8*)&stateL[0 * 2560 + c * 640 + ln * 40 + q * 8]);
        h16x8 a81 = __builtin_bit_cast(h16x8, *(const s16x8*)&stateL[1 * 2560 + c * 640 + ln * 40 + q * 8]);
        #pragma unroll
        for (int i = 0; i < 4; ++i) {
            int ct = w + 8 * i;               // 0..31
            h16x8 b8 = __builtin_bit_cast(h16x8, *(const s16x8*)&W1h[(size_t)(ct * 16 + ln) * CC + c * 32 + q * 8]);
            nacc[0][i] = __builtin_amdgcn_mfma_f32_16x16x32_f16(a80, b8, nacc[0][i], 0, 0, 0);
            nacc[1][i] = __builtin_amdgcn_mfma_f32_16x16x32_f16(a81, b8, nacc[1][i], 0, 0, 0);
        }
    }

    // ---- W2 strip loads issued HERE: latency hidden by nodeL writes+barrier
    s16x8 wa[16];
    #pragma unroll
    for (int c = 0; c < 16; ++c)
        wa[c] = *(const s16x8*)&W2h[(size_t)(w * 32 + l32) * HH + c * 16 + hf * 8];

    #pragma unroll
    for (int bt = 0; bt < 2; ++bt)
        #pragma unroll
        for (int i = 0; i < 4; ++i) {
            int col = (w + 8 * i) * 16 + ln;
            float wadd = (col < HH) ? wL[bt][col] : 0.f;
            #pragma unroll
            for (int rg = 0; rg < 4; ++rg) {
                int node = q * 4 + rg;
                if (node < ACT) nodeL[(bt * ACT + node) * NS + col] = f2h(nacc[bt][i][rg] + wadd);
            }
        }
    __syncthreads();   // nodeL visible; stateL now dead

    // cooperative H1 build (each element computed once), frag-order layout,
    // packed fp16 math: 3 VALU per 2 elements; edge pairs from LDS.
    const h16x2 c001 = {(_Float16)0.01f, (_Float16)0.01f};
    auto build = [&](int tile, int bufi) {
        int bt = (tile >= 6) ? 1 : 0;
        int e32 = t & 31;
        int e = (tile - bt * 6) * 32 + e32;
        bool ok = e < EPB;
        int2 p = edgeL[ok ? e : 0];
        int base = bt * ACT * NS;
        int uo = base + p.x * NS, vo = base + HH + p.y * NS;
        int sl = t >> 5;                       // 0..15
        #pragma unroll
        for (int s = 0; s < 2; ++s) {
            int slot = sl + 16 * s;            // 0..31
            int chunk = slot >> 1, half = slot & 1;
            int koff = chunk * 16 + half * 8;
            int o[4] = {0, 0, 0, 0};
            if (ok) {
                s16x8 u8 = *(const s16x8*)&nodeL[uo + koff];
                s16x8 v8 = *(const s16x8*)&nodeL[vo + koff];
                const int* ui = (const int*)&u8;
                const int* vi = (const int*)&v8;
                #pragma unroll
                for (int j = 0; j < 4; ++j) {
                    h16x2 uu = __builtin_bit_cast(h16x2, ui[j]);
                    h16x2 vv = __builtin_bit_cast(h16x2, vi[j]);
                    h16x2 sum = uu + vv;
                    h16x2 lk  = __builtin_elementwise_max(sum, sum * c001);
                    o[j] = __builtin_bit_cast(int, lk);
                }
            }
            *(s16x8*)&h1L[bufi][chunk * 512 + (half * 32 + e32) * 8] = *(const s16x8*)o;
        }
    };

    build(0, 0);
    for (int tile = 0; tile < 12; ++tile) {
        __syncthreads();
        if (tile < 11) build(tile + 1, (tile + 1) & 1);
        const int buf = tile & 1;
        f32x16 acc;
        #pragma unroll
        for (int r = 0; r < 16; ++r) acc[r] = 0.f;
        #pragma unroll
        for (int c = 0; c < 16; ++c) {
            h16x8 b8 = __builtin_bit_cast(h16x8, *(const s16x8*)&h1L[buf][c * 512 + lane * 8]);
            h16x8 a8 = __builtin_bit_cast(h16x8, wa[c]);
            acc = __builtin_amdgcn_mfma_f32_32x32x16_f16(a8, b8, acc, 0, 0, 0);
        }
        // in-lane epilogue: lane&31 = edge; regs r: n = w*32 + 4hf + 8g + i
        int bt = (tile >= 6) ? 1 : 0;
        int col0 = (tile - bt * 6) * 32;
        float pmu = 0.f, psg = 0.f;
        const int nsb = w * 32 + 4 * hf;
        #pragma unroll
        for (int g = 0; g < 4; ++g) {
            f32x4 b4 = *(const f32x4*)&b2L[nsb + 8 * g];     // 1x ds_read_b128
            i32x4 m4 = *(const i32x4*)&msL[nsb + 8 * g];     // 1x ds_read_b128
            #pragma unroll
            for (int i = 0; i < 4; ++i) {
                float h2 = leaky(acc[g * 4 + i] + b4[i]);
                pmu += bflo(m4[i]) * h2;
                psg += bfhi(m4[i]) * h2;
            }
        }
        pmu += __shfl_xor(pmu, 32);
        psg += __shfl_xor(psg, 32);
        if (lane < 32) atomicAdd(&mu_acc[bt * 192 + col0 + l32], pmu);
        else           atomicAdd(&sg_acc[bt * 192 + col0 + l32], psg);
    }
    __syncthreads();

    // ---- final head, both batches ----
    float lpv = 0.f;
    {
        int bt = t >> 8, i = t & 255;
        if (i < EPB) {
            float mu = softplusf(mu_acc[bt * 192 + i] + mu_b[0]);
            float sd = softplusf(sg_acc[bt * 192 + i] + sig_b[0]);
            float z = noise[(size_t)(2 * b + bt) * EPB + i];
            out[(size_t)(2 * b + bt) * EPB + i] = mu + sd * z;
            lpv = -0.5f * z * z - logf(sd);
        }
    }
    #pragma unroll
    for (int off = 1; off < 64; off <<= 1) lpv += __shfl_xor(lpv, off);
    if (lane == 0) atomicAdd(&lp_acc[t >> 8], lpv);
    __syncthreads();
    if (t < 2) out[M2 + 2 * b + t] = lp_acc[t] + LP_CONST;
}

// ---------------------------------------------------------------------------
extern "C" void kernel_launch(void* const* d_in, const int* in_sizes, int n_in,
                              void* d_out, int out_size, void* d_ws, size_t ws_size,
                              hipStream_t stream)
{
    const float* state  = (const float*)d_in[0];
    const float* conv_w = (const float*)d_in[1];
    const float* conv_b = (const float*)d_in[2];
    const float* lin1_w = (const float*)d_in[3];
    const float* lin1_b = (const float*)d_in[4];
    const float* lin2_w = (const float*)d_in[5];
    const float* lin2_b = (const float*)d_in[6];
    const float* mu_w   = (const float*)d_in[7];
    const float* mu_b   = (const float*)d_in[8];
    const float* sig_w  = (const float*)d_in[9];
    const float* sig_b  = (const float*)d_in[10];
    const float* noise  = (const float*)d_in[11];
    const int*   edges  = (const int*)d_in[13];
    float* out = (float*)d_out;

    char* ws = (char*)d_ws;
    short* W2h    = (short*)ws;  ws += 65536 * 2;
    short* W1h    = (short*)ws;  ws += 65536 * 2;
    int*   cwPT   = (int*)ws;    ws += 8192 * 4;
    int*   w1sPT  = (int*)ws;    ws += 16384 * 4;
    int*   msbf   = (int*)ws;    ws += 256 * 4;

    prep_kernel<<<256, 256, 0, stream>>>(conv_w, lin1_w, lin2_w, mu_w, sig_w,
                                         W2h, W1h, cwPT, w1sPT, msbf);
    actor_kernel<<<NB / 2, 512, 0, stream>>>(state, W1h, W2h,
                                             cwPT, conv_b, w1sPT, lin1_b,
                                             lin2_b, msbf, mu_b, sig_b,
                                             noise, edges, out);
}